// Round 6
// baseline (495.200 us; speedup 1.0000x reference)
//
#include <hip/hip_runtime.h>
#include <hip/hip_bf16.h>

#define N 8192
#define FIN 128
#define FOUT 64
#define CSPLIT 2
#define TILE_C 256            // adj cols per LDS tile
#define CHUNK (N / CSPLIT)    // 4096 cols per block
#define NT (CHUNK / TILE_C)   // 16 tiles
#define PASSES 2              // profiling doubling: num & den both x2 -> ratio exact

typedef __attribute__((ext_vector_type(4))) float f32x4;
typedef __attribute__((ext_vector_type(4))) int i32x4;
typedef __attribute__((ext_vector_type(8))) short bf16x8;

#define GLOAD_LDS16(gp, lp)                                                    \
    __builtin_amdgcn_global_load_lds(                                          \
        (const __attribute__((address_space(1))) void*)(gp),                   \
        (__attribute__((address_space(3))) void*)(lp), 16, 0, 0)

// Kernel 1: Wh = h @ W; s_src/s_dst; G1T[80][N] = e^{s_dst_j} * [Wh_j | 1 | 0...],
// G2T[80][N] = e^{0.2 s_dst_j} * [Wh_j | 1 | 0...]  (bf16, feature-major).
__global__ __launch_bounds__(256) void wh_kernel(
    const float* __restrict__ h, const float* __restrict__ W,
    const float* __restrict__ a,
    __hip_bfloat16* __restrict__ g1T, __hip_bfloat16* __restrict__ g2T,
    float* __restrict__ s_src, float* __restrict__ s_dst) {
    const int wave = threadIdx.x >> 6;
    const int lane = threadIdx.x & 63;   // lane = output feature f
    const int row = blockIdx.x * 4 + wave;
    const float* hr = h + (size_t)row * FIN;
    float acc = 0.f;
#pragma unroll 8
    for (int k = 0; k < FIN; ++k) {
        acc += hr[k] * W[k * FOUT + lane];
    }
    float s1 = acc * a[lane];
    float s2 = acc * a[FOUT + lane];
#pragma unroll
    for (int mm = 32; mm >= 1; mm >>= 1) {
        s1 += __shfl_xor(s1, mm, 64);   // butterfly: all lanes hold the sums
        s2 += __shfl_xor(s2, mm, 64);
    }
    const float e1 = __expf(s2);
    const float e2 = __expf(0.2f * s2);
    g1T[(size_t)lane * N + row] = __float2bfloat16(acc * e1);
    g2T[(size_t)lane * N + row] = __float2bfloat16(acc * e2);
    if (lane < 16) {                     // rows 64..79: den column + zero pad
        g1T[(size_t)(64 + lane) * N + row] = __float2bfloat16(lane == 0 ? e1 : 0.f);
        g2T[(size_t)(64 + lane) * N + row] = __float2bfloat16(lane == 0 ? e2 : 0.f);
    }
    if (lane == 0) { s_src[row] = s1; s_dst[row] = s2; }
}

// Kernel 2: masked-matmul attention partials. Inner loop: build 0/1 bf16 masks
// (adj & sign-split of s_i+s_j), 10 MFMAs against G1/G2 (80 cols; col 64 = den).
// adj staged via global_load_lds dbuf (R3 barriers) + XOR swizzle (R4, verified).
// Grid = (N/16)*CSPLIT. Block b: rg = b>>1 (16 rows), c = b&1 (4096 cols).
__global__ __launch_bounds__(256, 3) void gat_partial(
    const int* __restrict__ adj,
    const __hip_bfloat16* __restrict__ g1T, const __hip_bfloat16* __restrict__ g2T,
    const float* __restrict__ s_src, const float* __restrict__ s_dst,
    float* __restrict__ numP, float* __restrict__ denP) {
    union SMem {
        struct { int adjb[2][16][TILE_C]; float sdl[CHUNK]; } s;   // 32K + 16K
        struct { float pC1[4][16][FOUT]; float pC2[4][16][FOUT];
                 float pD1[4][16]; float pD2[4][16]; } e;          // 32.5K
    };
    __shared__ SMem sm;

    const int tid = threadIdx.x;
    const int w = tid >> 6, lane = tid & 63;
    const int m = lane & 15, kg = lane >> 4;
    const int rg = blockIdx.x >> 1;
    const int c = blockIdx.x & 1;
    const int ibase = rg * 16;
    const int cb = c * CHUNK;
    const float ti = -s_src[ibase + m];  // c1 <=> s_dst_j >= ti
    const int lane4 = lane * 4;
    const int sw = (m & 7) << 2;

    f32x4 acc1[5] = {{0,0,0,0},{0,0,0,0},{0,0,0,0},{0,0,0,0},{0,0,0,0}};
    f32x4 acc2[5] = {{0,0,0,0},{0,0,0,0},{0,0,0,0},{0,0,0,0},{0,0,0,0}};

    // stage s_dst chunk (16 KB) once
#pragma unroll
    for (int q = 0; q < 4; ++q) {
        const int j = 4 * w + q;
        GLOAD_LDS16(s_dst + cb + j * 256 + lane4, &sm.s.sdl[j * 256]);
    }

    for (int pass = 0; pass < PASSES; ++pass) {
        // stage tile 0 (source col pre-swizzled by row, rule #21)
#pragma unroll
        for (int q = 0; q < 4; ++q) {
            const int r = 4 * w + q;
            GLOAD_LDS16(adj + (size_t)(ibase + r) * N + cb + (lane4 ^ ((r & 7) << 2)),
                        &sm.s.adjb[0][r][0]);
        }
        __syncthreads();   // drains vmcnt -> tile 0 (and sdl) ready

        for (int t = 0; t < NT; ++t) {
            const int buf = t & 1;
            if (t + 1 < NT) {
                const int gcol = cb + (t + 1) * TILE_C;
#pragma unroll
                for (int q = 0; q < 4; ++q) {
                    const int r = 4 * w + q;
                    GLOAD_LDS16(adj + (size_t)(ibase + r) * N + gcol + (lane4 ^ ((r & 7) << 2)),
                                &sm.s.adjb[buf ^ 1][r][0]);
                }
            }
#pragma unroll
            for (int st = 0; st < 2; ++st) {
                const int tc = w * 64 + st * 32 + kg * 8;
                i32x4 a0 = *(const i32x4*)&sm.s.adjb[buf][m][tc ^ sw];
                i32x4 a1 = *(const i32x4*)&sm.s.adjb[buf][m][(tc + 4) ^ sw];
                f32x4 d0 = *(const f32x4*)&sm.s.sdl[t * TILE_C + tc];
                f32x4 d1 = *(const f32x4*)&sm.s.sdl[t * TILE_C + tc + 4];
                const size_t gc = (size_t)cb + t * TILE_C + tc;

                bf16x8 af1, af2;
#pragma unroll
                for (int e = 0; e < 4; ++e) {
                    unsigned t1 = (a0[e] != 0) ? 0x3F80u : 0u;   // bf16 1.0 if edge
                    unsigned v1 = (d0[e] >= ti) ? t1 : 0u;       // positive branch
                    af1[e] = (short)v1;
                    af2[e] = (short)(t1 ^ v1);                   // negative branch
                }
#pragma unroll
                for (int e = 0; e < 4; ++e) {
                    unsigned t1 = (a1[e] != 0) ? 0x3F80u : 0u;
                    unsigned v1 = (d1[e] >= ti) ? t1 : 0u;
                    af1[4 + e] = (short)v1;
                    af2[4 + e] = (short)(t1 ^ v1);
                }
#pragma unroll
                for (int q = 0; q < 5; ++q) {
                    bf16x8 b1 = *(const bf16x8*)(g1T + (size_t)(q * 16 + m) * N + gc);
                    bf16x8 b2 = *(const bf16x8*)(g2T + (size_t)(q * 16 + m) * N + gc);
                    acc1[q] = __builtin_amdgcn_mfma_f32_16x16x32_bf16(af1, b1, acc1[q], 0, 0, 0);
                    acc2[q] = __builtin_amdgcn_mfma_f32_16x16x32_bf16(af2, b2, acc2[q], 0, 0, 0);
                }
            }
            __syncthreads();   // stage(t+1) drained; all waves done with buf
        }
    }

    // epilogue: D lane l reg r -> row kg*4+r, col q*16+m
#pragma unroll
    for (int r = 0; r < 4; ++r) {
#pragma unroll
        for (int q = 0; q < 4; ++q) {
            sm.e.pC1[w][kg * 4 + r][q * 16 + m] = acc1[q][r];
            sm.e.pC2[w][kg * 4 + r][q * 16 + m] = acc2[q][r];
        }
    }
    if (m == 0) {   // frag q=4, col 64 (den) lives in lanes with m==0
#pragma unroll
        for (int r = 0; r < 4; ++r) {
            sm.e.pD1[w][kg * 4 + r] = acc1[4][r];
            sm.e.pD2[w][kg * 4 + r] = acc2[4][r];
        }
    }
    __syncthreads();

    float* numC = numP + (size_t)c * N * FOUT;
    float* denC = denP + (size_t)c * N;
#pragma unroll
    for (int k = 0; k < 4; ++k) {
        int idx = k * 256 + tid;
        int i = idx >> 6, f = idx & 63;
        float v1 = sm.e.pC1[0][i][f] + sm.e.pC1[1][i][f] + sm.e.pC1[2][i][f] + sm.e.pC1[3][i][f];
        float v2 = sm.e.pC2[0][i][f] + sm.e.pC2[1][i][f] + sm.e.pC2[2][i][f] + sm.e.pC2[3][i][f];
        float ss = s_src[ibase + i];
        float f1 = __expf(ss), f2 = __expf(0.2f * ss);
        numC[(size_t)(ibase + i) * FOUT + f] = f1 * v1 + f2 * v2;
        if (f == 0) {
            float d1 = sm.e.pD1[0][i] + sm.e.pD1[1][i] + sm.e.pD1[2][i] + sm.e.pD1[3][i];
            float d2 = sm.e.pD2[0][i] + sm.e.pD2[1][i] + sm.e.pD2[2][i] + sm.e.pD2[3][i];
            denC[ibase + i] = f1 * d1 + f2 * d2;
        }
    }
}

// Kernel 3: sum chunk partials, divide, ELU, store.
__global__ __launch_bounds__(256) void gat_combine(
    const float* __restrict__ numP, const float* __restrict__ denP,
    float* __restrict__ out) {
    int idx = blockIdx.x * 256 + threadIdx.x;
    int row = idx >> 6;
    float num = 0.f, den = 0.f;
#pragma unroll
    for (int cc = 0; cc < CSPLIT; ++cc) {
        num += numP[(size_t)cc * N * FOUT + idx];
        den += denP[(size_t)cc * N + row];
    }
    float v = num / den;
    out[idx] = (v > 0.f) ? v : expm1f(v);
}

extern "C" void kernel_launch(void* const* d_in, const int* in_sizes, int n_in,
                              void* d_out, int out_size, void* d_ws, size_t ws_size,
                              hipStream_t stream) {
    const float* h = (const float*)d_in[0];
    const int* adj = (const int*)d_in[1];
    const float* W = (const float*)d_in[2];
    const float* a = (const float*)d_in[3];
    float* out = (float*)d_out;

    char* ws = (char*)d_ws;
    __hip_bfloat16* g1T = (__hip_bfloat16*)ws;                       // 80*8192*2 = 1.31 MB
    __hip_bfloat16* g2T = g1T + (size_t)80 * N;                      // 1.31 MB
    float* s_src = (float*)(g2T + (size_t)80 * N);                   // 32 KB
    float* s_dst = s_src + N;                                        // 32 KB
    float* numP = s_dst + N;                                         // 4 MB
    float* denP = numP + (size_t)CSPLIT * N * FOUT;                  // 64 KB

    hipLaunchKernelGGL(wh_kernel, dim3(N / 4), dim3(256), 0, stream,
                       h, W, a, g1T, g2T, s_src, s_dst);
    hipLaunchKernelGGL(gat_partial, dim3((N / 16) * CSPLIT), dim3(256), 0, stream,
                       adj, g1T, g2T, s_src, s_dst, numP, denP);
    hipLaunchKernelGGL(gat_combine, dim3(N * FOUT / 256), dim3(256), 0, stream,
                       numP, denP, out);
}

// Round 7
// 88.539 us; speedup vs baseline: 5.5930x; 5.5930x over previous
//
#include <hip/hip_runtime.h>
#include <hip/hip_bf16.h>

#define N 8192
#define FIN 128
#define FOUT 64
#define CSPLIT 2
#define CHUNK (N / CSPLIT)     // 4096 cols per block
#define M 32                   // rows per block
#define TILE 128               // cols per tile
#define NT (CHUNK / TILE)      // 32 tiles

typedef __attribute__((ext_vector_type(4))) float f32x4;
typedef __attribute__((ext_vector_type(4))) int i32x4;
typedef __attribute__((ext_vector_type(8))) short bf16x8;

#define GLOAD_LDS16(gp, lp)                                                    \
    __builtin_amdgcn_global_load_lds(                                          \
        (const __attribute__((address_space(1))) void*)(gp),                   \
        (__attribute__((address_space(3))) void*)(lp), 16, 0, 0)

__device__ __forceinline__ short f2bf(float x) {
    __hip_bfloat16 b = __float2bfloat16(x);
    union { __hip_bfloat16 b; short s; } u; u.b = b; return u.s;
}

// Kernel 1: Wh = h @ W (store transposed bf16), s_src = Wh@a1, s_dst = Wh@a2
__global__ __launch_bounds__(256) void wh_kernel(
    const float* __restrict__ h, const float* __restrict__ W,
    const float* __restrict__ a,
    __hip_bfloat16* __restrict__ whT, float* __restrict__ s_src,
    float* __restrict__ s_dst) {
    const int wave = threadIdx.x >> 6;
    const int lane = threadIdx.x & 63;   // lane = output feature f
    const int row = blockIdx.x * 4 + wave;
    const float* hr = h + (size_t)row * FIN;
    float acc = 0.f;
#pragma unroll 8
    for (int k = 0; k < FIN; ++k) {
        acc += hr[k] * W[k * FOUT + lane];
    }
    whT[(size_t)lane * N + row] = __float2bfloat16(acc);
    float s1 = acc * a[lane];
    float s2 = acc * a[FOUT + lane];
#pragma unroll
    for (int mm = 32; mm >= 1; mm >>= 1) {
        s1 += __shfl_xor(s1, mm, 64);
        s2 += __shfl_xor(s2, mm, 64);
    }
    if (lane == 0) { s_src[row] = s1; s_dst[row] = s2; }
}

// Kernel 2: fused masked-softmax attention partials; ALL inner-loop operands
// (adj, whT, s_dst) staged in LDS. 8 waves; wave (wr,wc): rows wr*16..+16,
// cols wc*32 of each 128-col tile. Double-buffered, counted vmcnt(4), raw
// s_barrier (no vmcnt(0) drain in loop). Both-sides XOR swizzle (rule #21).
__global__ __launch_bounds__(512, 4) void gat_partial(
    const int* __restrict__ adj, const __hip_bfloat16* __restrict__ whT,
    const float* __restrict__ s_src, const float* __restrict__ s_dst,
    float* __restrict__ numP, float* __restrict__ denP) {
    union SMem {
        struct {
            int adjb[2][M][TILE];       // 32 KB (swizzled rows of 512B)
            short whb[2][FOUT][TILE];   // 32 KB (swizzled rows of 256B)
            float sdl[CHUNK];           // 16 KB
        } s;                            // 80 KB
        struct { float pC[4][M][FOUT]; float pD[4][M]; } e;  // 33 KB
    };
    __shared__ SMem sm;

    const int tid = threadIdx.x;
    const int w = tid >> 6, lane = tid & 63;
    const int m = lane & 15, kg = lane >> 4;
    const int wr = w >> 2, wc = w & 3;
    const int rg = blockIdx.x >> 1;
    const int c = blockIdx.x & 1;
    const int ibase = rg * M;
    const int cb = c * CHUNK;
    const float ssrc = s_src[ibase + wr * 16 + m];
    const int sidx = w * 2;            // this wave's 2 staging-instr indices

    f32x4 acc[4] = {{0,0,0,0},{0,0,0,0},{0,0,0,0},{0,0,0,0}};
    float dsum = 0.f;

    // stage tile t into buf: 2 adj instrs + 2 wh instrs per wave (uniform=4)
    auto stage = [&](int t, int buf) {
        const int gcol = cb + t * TILE;
#pragma unroll
        for (int q = 0; q < 2; ++q) {          // adj: instr idx covers 2 rows
            const int idx = sidx + q;
            const int r = idx * 2 + (lane >> 5);
            const int b = ((lane & 31) * 16) ^ ((r & 31) << 4);
            GLOAD_LDS16(adj + (size_t)(ibase + r) * N + gcol + (b >> 2),
                        &sm.s.adjb[buf][idx * 2][0]);
        }
#pragma unroll
        for (int q = 0; q < 2; ++q) {          // wh: instr idx covers 4 feat rows
            const int idx = sidx + q;
            const int f = idx * 4 + (lane >> 4);
            const int b = ((lane & 15) * 16) ^ ((f & 15) << 4);
            GLOAD_LDS16(whT + (size_t)f * N + gcol + (b >> 1),
                        &sm.s.whb[buf][idx * 4][0]);
        }
    };

    // prologue: sdl chunk (2 instrs/wave) + tiles 0,1
#pragma unroll
    for (int q = 0; q < 2; ++q) {
        const int idx = sidx + q;
        GLOAD_LDS16(s_dst + cb + idx * 256 + lane * 4, &sm.s.sdl[idx * 256]);
    }
    stage(0, 0);
    stage(1, 1);
    asm volatile("s_waitcnt vmcnt(4)" ::: "memory");   // sdl + tile0 done
    __builtin_amdgcn_s_barrier();

#pragma unroll 2
    for (int t = 0; t < NT; ++t) {
        const int buf = t & 1;

        // ---- compute tile t (LDS only) ----
        {
            const int kcol = wc * 32 + kg * 8;
            const int aRow = wr * 16 + m;
            const char* adjbase = (const char*)&sm.s.adjb[buf][0][0];
            const int aswz = (aRow & 31) << 4;
            i32x4 a0 = *(const i32x4*)(adjbase + aRow * 512 + ((kcol * 4) ^ aswz));
            i32x4 a1 = *(const i32x4*)(adjbase + aRow * 512 + ((kcol * 4 + 16) ^ aswz));
            f32x4 d0 = *(const f32x4*)&sm.s.sdl[t * TILE + kcol];
            f32x4 d1 = *(const f32x4*)&sm.s.sdl[t * TILE + kcol + 4];
            const char* whbase = (const char*)&sm.s.whb[buf][0][0];
            bf16x8 bq0 = *(const bf16x8*)(whbase + (0 * 16 + m) * 256 + ((kcol * 2) ^ (m << 4)));
            bf16x8 bq1 = *(const bf16x8*)(whbase + (1 * 16 + m) * 256 + ((kcol * 2) ^ (m << 4)));
            bf16x8 bq2 = *(const bf16x8*)(whbase + (2 * 16 + m) * 256 + ((kcol * 2) ^ (m << 4)));
            bf16x8 bq3 = *(const bf16x8*)(whbase + (3 * 16 + m) * 256 + ((kcol * 2) ^ (m << 4)));

            bf16x8 afr;
#pragma unroll
            for (int e = 0; e < 4; ++e) {
                float x = ssrc + d0[e];
                x = (x >= 0.f) ? x : 0.2f * x;
                float p = (a0[e] != 0) ? __expf(x) : 0.f;
                dsum += p;
                afr[e] = f2bf(p);
            }
#pragma unroll
            for (int e = 0; e < 4; ++e) {
                float x = ssrc + d1[e];
                x = (x >= 0.f) ? x : 0.2f * x;
                float p = (a1[e] != 0) ? __expf(x) : 0.f;
                dsum += p;
                afr[4 + e] = f2bf(p);
            }

            acc[0] = __builtin_amdgcn_mfma_f32_16x16x32_bf16(afr, bq0, acc[0], 0, 0, 0);
            acc[1] = __builtin_amdgcn_mfma_f32_16x16x32_bf16(afr, bq1, acc[1], 0, 0, 0);
            acc[2] = __builtin_amdgcn_mfma_f32_16x16x32_bf16(afr, bq2, acc[2], 0, 0, 0);
            acc[3] = __builtin_amdgcn_mfma_f32_16x16x32_bf16(afr, bq3, acc[3], 0, 0, 0);
        }

        __builtin_amdgcn_s_barrier();          // all waves done reading buf
        if (t + 2 < NT) {
            stage(t + 2, buf);                 // refill buf with tile t+2
            asm volatile("s_waitcnt vmcnt(4)" ::: "memory");  // tile t+1 ready
            __builtin_amdgcn_s_barrier();
        } else if (t + 1 < NT) {
            asm volatile("s_waitcnt vmcnt(0)" ::: "memory");  // last tile ready
            __builtin_amdgcn_s_barrier();
        }
    }

    // denominator: lanes l, l^16, l^32, l^48 share row m
    dsum += __shfl_xor(dsum, 16, 64);
    dsum += __shfl_xor(dsum, 32, 64);

    // epilogue (all waves passed the final barrier -> safe to reuse LDS)
#pragma unroll
    for (int r = 0; r < 4; ++r) {
#pragma unroll
        for (int q = 0; q < 4; ++q) {
            sm.e.pC[wc][wr * 16 + kg * 4 + r][q * 16 + m] = acc[q][r];
        }
    }
    if (kg == 0) sm.e.pD[wc][wr * 16 + m] = dsum;
    __syncthreads();

    float* numC = numP + (size_t)c * N * FOUT;
    float* denC = denP + (size_t)c * N;
#pragma unroll
    for (int k = 0; k < 4; ++k) {
        int idx = k * 512 + tid;
        int i = idx >> 6, f = idx & 63;
        float num = sm.e.pC[0][i][f] + sm.e.pC[1][i][f] + sm.e.pC[2][i][f] + sm.e.pC[3][i][f];
        numC[(size_t)(ibase + i) * FOUT + f] = num;
        if (f == 0) {
            denC[ibase + i] = sm.e.pD[0][i] + sm.e.pD[1][i] + sm.e.pD[2][i] + sm.e.pD[3][i];
        }
    }
}

// Kernel 3: sum chunk partials, divide, ELU, store.
__global__ __launch_bounds__(256) void gat_combine(
    const float* __restrict__ numP, const float* __restrict__ denP,
    float* __restrict__ out) {
    int idx = blockIdx.x * 256 + threadIdx.x;
    int row = idx >> 6;
    float num = 0.f, den = 0.f;
#pragma unroll
    for (int cc = 0; cc < CSPLIT; ++cc) {
        num += numP[(size_t)cc * N * FOUT + idx];
        den += denP[(size_t)cc * N + row];
    }
    float v = num / den;
    out[idx] = (v > 0.f) ? v : expm1f(v);
}

extern "C" void kernel_launch(void* const* d_in, const int* in_sizes, int n_in,
                              void* d_out, int out_size, void* d_ws, size_t ws_size,
                              hipStream_t stream) {
    const float* h = (const float*)d_in[0];
    const int* adj = (const int*)d_in[1];
    const float* W = (const float*)d_in[2];
    const float* a = (const float*)d_in[3];
    float* out = (float*)d_out;

    char* ws = (char*)d_ws;
    __hip_bfloat16* whT = (__hip_bfloat16*)ws;                       // 1 MB
    float* s_src = (float*)(ws + (size_t)FOUT * N * sizeof(__hip_bfloat16));
    float* s_dst = s_src + N;                                        // +64 KB
    float* numP = s_dst + N;                                         // 4 MB
    float* denP = numP + (size_t)CSPLIT * N * FOUT;                  // 64 KB

    hipLaunchKernelGGL(wh_kernel, dim3(N / 4), dim3(256), 0, stream,
                       h, W, a, whT, s_src, s_dst);
    hipLaunchKernelGGL(gat_partial, dim3((N / M) * CSPLIT), dim3(512), 0, stream,
                       adj, whT, s_src, s_dst, numP, denP);
    hipLaunchKernelGGL(gat_combine, dim3(N * FOUT / 256), dim3(256), 0, stream,
                       numP, denP, out);
}